// Round 6
// baseline (185.486 us; speedup 1.0000x reference)
//
#include <hip/hip_runtime.h>
#include <hip/hip_bf16.h>
#include <cstddef>

#define NBATCH 16384
#define NNB 32
#define DD 128
#define NH 4
#define NHD 512   // NH * DD
#define BB 16     // batches per block
#define NT 512    // threads per block

// bf16 pack/unpack helpers (round-to-nearest-even pack; unpack = <<16)
__device__ __forceinline__ unsigned f2bf1(float f) {
  unsigned u = __float_as_uint(f);
  return (u + 0x7FFFu + ((u >> 16) & 1u)) >> 16;
}
__device__ __forceinline__ unsigned pack2bf(float lo, float hi) {
  return f2bf1(lo) | (f2bf1(hi) << 16);
}
__device__ __forceinline__ float bflo(unsigned u) { return __uint_as_float(u << 16); }
__device__ __forceinline__ float bfhi(unsigned u) { return __uint_as_float(u & 0xFFFF0000u); }

// ---------------------------------------------------------------------------
// K0: precompute A_all[i][h*128+d] = sum_r Wq[h][r][i] * Wk[h][r][d]   (fp32)
//     and       C_all[h*128+i][o]  = 0.25 * sum_d Wo[o][d]*Wv[h][d][i] (bf16)
// ---------------------------------------------------------------------------
__global__ __launch_bounds__(256) void precompute_kernel(
    const float* __restrict__ Wq, const float* __restrict__ Wk,
    const float* __restrict__ Wv, const float* __restrict__ Wo,
    float* __restrict__ AA, unsigned short* __restrict__ CC16) {
  int e = blockIdx.x * 256 + threadIdx.x;   // 0..65535
  if (blockIdx.y == 0) {
    int i = e >> 9;            // 0..127
    int hd = e & 511;
    int h = hd >> 7, d = hd & 127;
    const float* wq = Wq + h * 16384;
    const float* wk = Wk + h * 16384;
    float acc = 0.f;
    #pragma unroll 8
    for (int r = 0; r < 128; ++r) acc += wq[r * 128 + i] * wk[r * 128 + d];
    AA[e] = acc;
  } else {
    int hi = e >> 7;           // 0..511
    int o = e & 127;
    int h = hi >> 7, i = hi & 127;
    const float* wv = Wv + h * 16384;
    float acc = 0.f;
    #pragma unroll 8
    for (int d = 0; d < 128; ++d) acc += Wo[o * 128 + d] * wv[d * 128 + i];
    CC16[e] = (unsigned short)f2bf1(0.25f * acc);
  }
}

// ---------------------------------------------------------------------------
// Fused kernel, R6: LDS diet 80->52 KB (3 blocks/CU, 24 waves) —
//  - x_lds dropped (phase-1 x reads are wave-uniform global broadcasts)
//  - ws_lds, attn_lds, CC in bf16 (error budget ~3e-3 vs 1.36e-2 threshold)
//  - g_lds fp32 (logit precision), reused for phase-3 partials
// ---------------------------------------------------------------------------
__global__ __launch_bounds__(NT, 4) void fused_kernel(
    const float* __restrict__ x, const float* __restrict__ nb,
    const float* __restrict__ AA, const unsigned short* __restrict__ CC16,
    const float* __restrict__ bo, float* __restrict__ out) {

  __shared__ __align__(16) float g_lds[BB][NHD];       // 32 KB (reused as partials)
  __shared__ __align__(16) unsigned ws16[BB][NHD / 2]; // 16 KB (bf16 pairs: cols 2i,2i+1)
  __shared__ __align__(16) unsigned attn16[BB][NNB * 2]; // 4 KB (bf16 pairs: h pairs)

  const int t = threadIdx.x;
  const int b0 = blockIdx.x * BB;

  // ---- phase 1: g[b][hd] = sum_i x[b][i] * AA[i][hd]
  {
    const int hdq = t & 127;   // hd = 4*hdq
    const int bq  = t >> 7;    // batches 4*bq .. 4*bq+3 (wave-uniform)
    const float4* AA4 = (const float4*)AA;   // [128 rows][128 float4 cols]
    const float* xbase = x + (size_t)(b0 + 4 * bq) * DD;
    float4 acc[4];
    #pragma unroll
    for (int j = 0; j < 4; ++j) acc[j] = make_float4(0.f, 0.f, 0.f, 0.f);
    #pragma unroll 2
    for (int i4 = 0; i4 < 128; i4 += 4) {
      float4 a0 = AA4[(i4 + 0) * 128 + hdq];
      float4 a1 = AA4[(i4 + 1) * 128 + hdq];
      float4 a2 = AA4[(i4 + 2) * 128 + hdq];
      float4 a3 = AA4[(i4 + 3) * 128 + hdq];
      #pragma unroll
      for (int j = 0; j < 4; ++j) {
        // wave-uniform address -> single-line broadcast fetch (scalar-cache class)
        float4 xv = *(const float4*)(xbase + j * DD + i4);
        acc[j].x += xv.x * a0.x + xv.y * a1.x + xv.z * a2.x + xv.w * a3.x;
        acc[j].y += xv.x * a0.y + xv.y * a1.y + xv.z * a2.y + xv.w * a3.y;
        acc[j].z += xv.x * a0.z + xv.y * a1.z + xv.z * a2.z + xv.w * a3.z;
        acc[j].w += xv.x * a0.w + xv.y * a1.w + xv.z * a2.w + xv.w * a3.w;
      }
    }
    #pragma unroll
    for (int j = 0; j < 4; ++j)
      *(float4*)&g_lds[4 * bq + j][4 * hdq] = acc[j];
  }
  __syncthreads();

  // ---- phase 2: attention, streaming two-pass; wave owns 2 batches
  {
    const int wv_ = t >> 6;        // wave 0..7
    const int lane = t & 63;
    const int n = lane & 31, half = lane >> 5;
    #pragma unroll 1
    for (int c = 0; c < 2; ++c) {
      const int b = 2 * wv_ + c;
      // ---- pass A: logits. lane reads neighbor n's half-row, streaming.
      const float* nrow = nb + ((size_t)(b0 + b) * NNB + n) * DD + half * 64;
      float acc0 = 0.f, acc1 = 0.f, acc2 = 0.f, acc3 = 0.f;
      #pragma unroll
      for (int j = 0; j < 16; ++j) {
        float4 f = ((const float4*)nrow)[j];
        float4 g0 = *(const float4*)&g_lds[b][0 * DD + half * 64 + 4 * j];
        float4 g1 = *(const float4*)&g_lds[b][1 * DD + half * 64 + 4 * j];
        float4 g2 = *(const float4*)&g_lds[b][2 * DD + half * 64 + 4 * j];
        float4 g3 = *(const float4*)&g_lds[b][3 * DD + half * 64 + 4 * j];
        acc0 += f.x * g0.x + f.y * g0.y + f.z * g0.z + f.w * g0.w;
        acc1 += f.x * g1.x + f.y * g1.y + f.z * g1.z + f.w * g1.w;
        acc2 += f.x * g2.x + f.y * g2.y + f.z * g2.z + f.w * g2.w;
        acc3 += f.x * g3.x + f.y * g3.y + f.z * g3.z + f.w * g3.w;
      }
      // combine halves: lanes (n, n+32) both get the full logit
      float lg0 = acc0 + __shfl_xor(acc0, 32);
      float lg1 = acc1 + __shfl_xor(acc1, 32);
      float lg2 = acc2 + __shfl_xor(acc2, 32);
      float lg3 = acc3 + __shfl_xor(acc3, 32);
      // softmax over the 32 n's (each 32-lane half holds all 32 n's)
      float4 aw;
      {
        float m0 = lg0, m1 = lg1, m2 = lg2, m3 = lg3;
        #pragma unroll
        for (int off = 16; off >= 1; off >>= 1) {
          m0 = fmaxf(m0, __shfl_xor(m0, off));
          m1 = fmaxf(m1, __shfl_xor(m1, off));
          m2 = fmaxf(m2, __shfl_xor(m2, off));
          m3 = fmaxf(m3, __shfl_xor(m3, off));
        }
        float e0 = __expf(lg0 - m0), e1 = __expf(lg1 - m1);
        float e2 = __expf(lg2 - m2), e3 = __expf(lg3 - m3);
        float s0 = e0, s1 = e1, s2 = e2, s3 = e3;
        #pragma unroll
        for (int off = 16; off >= 1; off >>= 1) {
          s0 += __shfl_xor(s0, off);
          s1 += __shfl_xor(s1, off);
          s2 += __shfl_xor(s2, off);
          s3 += __shfl_xor(s3, off);
        }
        aw = make_float4(e0 / s0, e1 / s1, e2 / s2, e3 / s3);
      }
      if (half == 0) {
        attn16[b][n * 2 + 0] = pack2bf(aw.x, aw.y);
        attn16[b][n * 2 + 1] = pack2bf(aw.z, aw.w);
      }
      // ---- pass B: weighted sum. lane owns columns (2*lane, 2*lane+1).
      float w00 = 0.f, w01 = 0.f, w10 = 0.f, w11 = 0.f;
      float w20 = 0.f, w21 = 0.f, w30 = 0.f, w31 = 0.f;
      const float* nbb = nb + (size_t)(b0 + b) * (NNB * DD);
      #pragma unroll 8
      for (int n2 = 0; n2 < NNB; ++n2) {
        float2 f2 = *(const float2*)(nbb + n2 * DD + 2 * lane);
        uint2 au = *(const uint2*)&attn16[b][n2 * 2];   // uniform broadcast
        float a0 = bflo(au.x), a1 = bfhi(au.x);
        float a2 = bflo(au.y), a3 = bfhi(au.y);
        w00 += a0 * f2.x; w01 += a0 * f2.y;
        w10 += a1 * f2.x; w11 += a1 * f2.y;
        w20 += a2 * f2.x; w21 += a2 * f2.y;
        w30 += a3 * f2.x; w31 += a3 * f2.y;
      }
      ws16[b][0 * 64 + lane] = pack2bf(w00, w01);
      ws16[b][1 * 64 + lane] = pack2bf(w10, w11);
      ws16[b][2 * 64 + lane] = pack2bf(w20, w21);
      ws16[b][3 * 64 + lane] = pack2bf(w30, w31);
    }
  }
  __syncthreads();

  // ---- phase 3: gemm2 partials, k split across 4 thread groups (bf16 ws/CC)
  {
    const int oq = t & 31;         // o = 4*oq
    const int bq = (t >> 5) & 3;   // batches 4*bq .. 4*bq+3
    const int kg = t >> 7;         // k range kg*128 .. +127
    float4 acc[4];
    #pragma unroll
    for (int j = 0; j < 4; ++j) acc[j] = make_float4(0.f, 0.f, 0.f, 0.f);
    const int kbase = kg * 128;
    #pragma unroll 2
    for (int kk = 0; kk < 128; kk += 4) {
      const int k = kbase + kk;
      uint2 cu0 = *(const uint2*)(CC16 + (size_t)(k + 0) * DD + 4 * oq);
      uint2 cu1 = *(const uint2*)(CC16 + (size_t)(k + 1) * DD + 4 * oq);
      uint2 cu2 = *(const uint2*)(CC16 + (size_t)(k + 2) * DD + 4 * oq);
      uint2 cu3 = *(const uint2*)(CC16 + (size_t)(k + 3) * DD + 4 * oq);
      float4 c0 = make_float4(bflo(cu0.x), bfhi(cu0.x), bflo(cu0.y), bfhi(cu0.y));
      float4 c1 = make_float4(bflo(cu1.x), bfhi(cu1.x), bflo(cu1.y), bfhi(cu1.y));
      float4 c2 = make_float4(bflo(cu2.x), bfhi(cu2.x), bflo(cu2.y), bfhi(cu2.y));
      float4 c3 = make_float4(bflo(cu3.x), bfhi(cu3.x), bflo(cu3.y), bfhi(cu3.y));
      #pragma unroll
      for (int j = 0; j < 4; ++j) {
        uint2 wu = *(const uint2*)&ws16[4 * bq + j][k / 2];  // 2-addr broadcast
        float w0 = bflo(wu.x), w1 = bfhi(wu.x);
        float w2 = bflo(wu.y), w3 = bfhi(wu.y);
        acc[j].x += w0 * c0.x + w1 * c1.x + w2 * c2.x + w3 * c3.x;
        acc[j].y += w0 * c0.y + w1 * c1.y + w2 * c2.y + w3 * c3.y;
        acc[j].z += w0 * c0.z + w1 * c1.z + w2 * c2.z + w3 * c3.z;
        acc[j].w += w0 * c0.w + w1 * c1.w + w2 * c2.w + w3 * c3.w;
      }
    }
    // partials into g_lds (dead after phase 2): [4 kg][16 b][128 o] = 32 KB
    float* part = (float*)g_lds;
    #pragma unroll
    for (int j = 0; j < 4; ++j)
      *(float4*)&part[((kg * BB) + (4 * bq + j)) * DD + 4 * oq] = acc[j];
  }
  __syncthreads();

  // ---- phase 4: reduce partials + bias + leaky relu + store
  {
    const int o4 = t & 31;
    const int b  = t >> 5;   // 0..15
    const float* part = (const float*)g_lds;
    float4 p0 = *(const float4*)&part[(0 * BB + b) * DD + 4 * o4];
    float4 p1 = *(const float4*)&part[(1 * BB + b) * DD + 4 * o4];
    float4 p2 = *(const float4*)&part[(2 * BB + b) * DD + 4 * o4];
    float4 p3 = *(const float4*)&part[(3 * BB + b) * DD + 4 * o4];
    float4 bias = ((const float4*)bo)[o4];
    float r0 = p0.x + p1.x + p2.x + p3.x + bias.x;
    float r1 = p0.y + p1.y + p2.y + p3.y + bias.y;
    float r2 = p0.z + p1.z + p2.z + p3.z + bias.z;
    float r3 = p0.w + p1.w + p2.w + p3.w + bias.w;
    float4 r;
    r.x = r0 > 0.f ? r0 : 0.01f * r0;
    r.y = r1 > 0.f ? r1 : 0.01f * r1;
    r.z = r2 > 0.f ? r2 : 0.01f * r2;
    r.w = r3 > 0.f ? r3 : 0.01f * r3;
    ((float4*)(out + (size_t)(b0 + b) * DD))[o4] = r;
  }
}

// ---------------------------------------------------------------------------
extern "C" void kernel_launch(void* const* d_in, const int* in_sizes, int n_in,
                              void* d_out, int out_size, void* d_ws, size_t ws_size,
                              hipStream_t stream) {
  const float* x  = (const float*)d_in[0];
  const float* nb = (const float*)d_in[1];
  const float* Wq = (const float*)d_in[2];
  const float* Wk = (const float*)d_in[3];
  const float* Wv = (const float*)d_in[4];
  const float* Wo = (const float*)d_in[5];
  const float* bo = (const float*)d_in[6];
  float* out = (float*)d_out;

  float* ws = (float*)d_ws;
  float* AA = ws;                                    // [128][512] fp32, 256 KB
  unsigned short* CC16 = (unsigned short*)(ws + 65536); // [512][128] bf16, 128 KB

  precompute_kernel<<<dim3(256, 2), 256, 0, stream>>>(Wq, Wk, Wv, Wo, AA, CC16);
  fused_kernel<<<dim3(NBATCH / BB), NT, 0, stream>>>(x, nb, AA, CC16, bo, out);
}

// Round 7
// 125.224 us; speedup vs baseline: 1.4812x; 1.4812x over previous
//
#include <hip/hip_runtime.h>
#include <hip/hip_bf16.h>
#include <cstddef>

#define NBATCH 16384
#define NNB 32
#define DD 128
#define NH 4
#define NHD 512   // NH * DD
#define BB 16     // batches per block
#define NT 512    // threads per block
#define WSU 260   // ws16 row stride in uints (256 + 4 pad -> odd multiple of 16B)

typedef __attribute__((ext_vector_type(8))) short short8v;  // 8 bf16 (4 VGPRs)
typedef __attribute__((ext_vector_type(4))) float f32x4;

// bf16 pack helpers (round-to-nearest-even)
__device__ __forceinline__ unsigned f2bf1(float f) {
  unsigned u = __float_as_uint(f);
  return (u + 0x7FFFu + ((u >> 16) & 1u)) >> 16;
}
__device__ __forceinline__ unsigned pack2bf(float lo, float hi) {
  return f2bf1(lo) | (f2bf1(hi) << 16);
}
__device__ __forceinline__ float bflo(unsigned u) { return __uint_as_float(u << 16); }
__device__ __forceinline__ float bfhi(unsigned u) { return __uint_as_float(u & 0xFFFF0000u); }

// ---------------------------------------------------------------------------
// K0: AA[i][h*128+d] = sum_r Wq[h][r][i]*Wk[h][r][d]                  (fp32)
//     CCf = 0.25 * Wo@Wv, stored bf16 in MFMA B-FRAGMENT order:
//       frag (ntile t, kstep s): lane l, elem e  <->  CC[k][o],
//       o = t*16 + (l&15), k = s*32 + (l>>4)*8 + e
//       ushort idx = ((t*16+s)*64 + l)*8 + e   -> lane loads = coalesced b128
// ---------------------------------------------------------------------------
__global__ __launch_bounds__(256) void precompute_kernel(
    const float* __restrict__ Wq, const float* __restrict__ Wk,
    const float* __restrict__ Wv, const float* __restrict__ Wo,
    float* __restrict__ AA, unsigned short* __restrict__ CCf) {
  int e = blockIdx.x * 256 + threadIdx.x;   // 0..65535
  if (blockIdx.y == 0) {
    int i = e >> 9;            // 0..127
    int hd = e & 511;
    int h = hd >> 7, d = hd & 127;
    const float* wq = Wq + h * 16384;
    const float* wk = Wk + h * 16384;
    float acc = 0.f;
    #pragma unroll 8
    for (int r = 0; r < 128; ++r) acc += wq[r * 128 + i] * wk[r * 128 + d];
    AA[e] = acc;
  } else {
    int k = e >> 7;            // 0..511  (k = h*128 + i)
    int o = e & 127;
    int h = k >> 7, i = k & 127;
    const float* wv = Wv + h * 16384;
    float acc = 0.f;
    #pragma unroll 8
    for (int d = 0; d < 128; ++d) acc += Wo[o * 128 + d] * wv[d * 128 + i];
    int t = o >> 4, s = k >> 5, g = (k >> 3) & 3, eo = k & 7;
    int lane = (o & 15) + 16 * g;
    size_t idx = ((size_t)(t * 16 + s) * 64 + lane) * 8 + eo;
    CCf[idx] = (unsigned short)f2bf1(0.25f * acc);
  }
}

// ---------------------------------------------------------------------------
// Fused kernel R7: phase1 = R5 (fp32 VALU, x in LDS); phase2 = R5/R6 streaming
// attention (ws packed bf16 into padded A-fragment rows); phase3 = bf16 MFMA
// (ws16 A-frags from LDS, CCf B-frags coalesced from L2), bias+leaky fused.
// ---------------------------------------------------------------------------
__global__ __launch_bounds__(NT, 4) void fused_kernel(
    const float* __restrict__ x, const float* __restrict__ nb,
    const float* __restrict__ AA, const unsigned short* __restrict__ CCf,
    const float* __restrict__ bo, float* __restrict__ out) {

  __shared__ __align__(16) float x_lds[BB][DD];          // 8 KB
  __shared__ __align__(16) float g_lds[BB][NHD];         // 32 KB
  __shared__ __align__(16) unsigned ws16[BB][WSU];       // 16.25 KB (bf16 pairs, padded)
  __shared__ __align__(16) unsigned attn16[BB][NNB * 2]; // 4 KB

  const int t = threadIdx.x;
  const int b0 = blockIdx.x * BB;

  // ---- phase 0: stage x rows
  {
    float4 v = ((const float4*)(x + (size_t)b0 * DD))[t];
    ((float4*)x_lds)[t] = v;
  }
  __syncthreads();

  // ---- phase 1: g[b][hd] = sum_i x[b][i] * AA[i][hd]   (fp32 VALU)
  {
    const int hdq = t & 127;   // hd = 4*hdq
    const int bq  = t >> 7;    // batches 4*bq .. 4*bq+3
    const float4* AA4 = (const float4*)AA;   // [128][128] float4
    float4 acc[4];
    #pragma unroll
    for (int j = 0; j < 4; ++j) acc[j] = make_float4(0.f, 0.f, 0.f, 0.f);
    #pragma unroll 2
    for (int i4 = 0; i4 < 128; i4 += 4) {
      float4 a0 = AA4[(i4 + 0) * 128 + hdq];
      float4 a1 = AA4[(i4 + 1) * 128 + hdq];
      float4 a2 = AA4[(i4 + 2) * 128 + hdq];
      float4 a3 = AA4[(i4 + 3) * 128 + hdq];
      #pragma unroll
      for (int j = 0; j < 4; ++j) {
        float4 xv = *(const float4*)&x_lds[4 * bq + j][i4];  // wave-uniform
        acc[j].x += xv.x * a0.x + xv.y * a1.x + xv.z * a2.x + xv.w * a3.x;
        acc[j].y += xv.x * a0.y + xv.y * a1.y + xv.z * a2.y + xv.w * a3.y;
        acc[j].z += xv.x * a0.z + xv.y * a1.z + xv.z * a2.z + xv.w * a3.z;
        acc[j].w += xv.x * a0.w + xv.y * a1.w + xv.z * a2.w + xv.w * a3.w;
      }
    }
    #pragma unroll
    for (int j = 0; j < 4; ++j)
      *(float4*)&g_lds[4 * bq + j][4 * hdq] = acc[j];
  }
  __syncthreads();

  // ---- phase 2: attention, streaming two-pass; wave owns 2 batches
  {
    const int wv_ = t >> 6;        // wave 0..7
    const int lane = t & 63;
    const int n = lane & 31, half = lane >> 5;
    #pragma unroll 1
    for (int c = 0; c < 2; ++c) {
      const int b = 2 * wv_ + c;
      // pass A: logits, nb streamed (lane = (n, half) owns a half-row)
      const float* nrow = nb + ((size_t)(b0 + b) * NNB + n) * DD + half * 64;
      float acc0 = 0.f, acc1 = 0.f, acc2 = 0.f, acc3 = 0.f;
      #pragma unroll
      for (int j = 0; j < 16; ++j) {
        float4 f = ((const float4*)nrow)[j];
        float4 g0 = *(const float4*)&g_lds[b][0 * DD + half * 64 + 4 * j];
        float4 g1 = *(const float4*)&g_lds[b][1 * DD + half * 64 + 4 * j];
        float4 g2 = *(const float4*)&g_lds[b][2 * DD + half * 64 + 4 * j];
        float4 g3 = *(const float4*)&g_lds[b][3 * DD + half * 64 + 4 * j];
        acc0 += f.x * g0.x + f.y * g0.y + f.z * g0.z + f.w * g0.w;
        acc1 += f.x * g1.x + f.y * g1.y + f.z * g1.z + f.w * g1.w;
        acc2 += f.x * g2.x + f.y * g2.y + f.z * g2.z + f.w * g2.w;
        acc3 += f.x * g3.x + f.y * g3.y + f.z * g3.z + f.w * g3.w;
      }
      float lg0 = acc0 + __shfl_xor(acc0, 32);
      float lg1 = acc1 + __shfl_xor(acc1, 32);
      float lg2 = acc2 + __shfl_xor(acc2, 32);
      float lg3 = acc3 + __shfl_xor(acc3, 32);
      float4 aw;
      {
        float m0 = lg0, m1 = lg1, m2 = lg2, m3 = lg3;
        #pragma unroll
        for (int off = 16; off >= 1; off >>= 1) {
          m0 = fmaxf(m0, __shfl_xor(m0, off));
          m1 = fmaxf(m1, __shfl_xor(m1, off));
          m2 = fmaxf(m2, __shfl_xor(m2, off));
          m3 = fmaxf(m3, __shfl_xor(m3, off));
        }
        float e0 = __expf(lg0 - m0), e1 = __expf(lg1 - m1);
        float e2 = __expf(lg2 - m2), e3 = __expf(lg3 - m3);
        float s0 = e0, s1 = e1, s2 = e2, s3 = e3;
        #pragma unroll
        for (int off = 16; off >= 1; off >>= 1) {
          s0 += __shfl_xor(s0, off);
          s1 += __shfl_xor(s1, off);
          s2 += __shfl_xor(s2, off);
          s3 += __shfl_xor(s3, off);
        }
        aw = make_float4(e0 / s0, e1 / s1, e2 / s2, e3 / s3);
      }
      if (half == 0) {
        attn16[b][n * 2 + 0] = pack2bf(aw.x, aw.y);
        attn16[b][n * 2 + 1] = pack2bf(aw.z, aw.w);
      }
      // pass B: weighted sum; lane owns cols (2*lane, 2*lane+1); L1/L2-hot re-read
      float w00 = 0.f, w01 = 0.f, w10 = 0.f, w11 = 0.f;
      float w20 = 0.f, w21 = 0.f, w30 = 0.f, w31 = 0.f;
      const float* nbb = nb + (size_t)(b0 + b) * (NNB * DD);
      #pragma unroll 8
      for (int n2 = 0; n2 < NNB; ++n2) {
        float2 f2 = *(const float2*)(nbb + n2 * DD + 2 * lane);
        uint2 au = *(const uint2*)&attn16[b][n2 * 2];   // uniform broadcast
        float a0 = bflo(au.x), a1 = bfhi(au.x);
        float a2 = bflo(au.y), a3 = bfhi(au.y);
        w00 += a0 * f2.x; w01 += a0 * f2.y;
        w10 += a1 * f2.x; w11 += a1 * f2.y;
        w20 += a2 * f2.x; w21 += a2 * f2.y;
        w30 += a3 * f2.x; w31 += a3 * f2.y;
      }
      // ws row b: uint u holds cols (2u, 2u+1) -> matches A-frag k pairing
      ws16[b][0 * 64 + lane] = pack2bf(w00, w01);
      ws16[b][1 * 64 + lane] = pack2bf(w10, w11);
      ws16[b][2 * 64 + lane] = pack2bf(w20, w21);
      ws16[b][3 * 64 + lane] = pack2bf(w30, w31);
    }
  }
  __syncthreads();

  // ---- phase 3: OUT[16,128] = WS[16,512] @ CC[512,128] via bf16 MFMA
  // wave w owns n-tile w (cols w*16..w*16+15); 16 k-steps of K=32.
  // A-frag: lane l -> ws row (l&15), k = (l>>4)*8 + e  (uints (l>>4)*4..+3)
  // B-frag: coalesced uint4 from CCf (pre-laid in matching order)
  {
    const int w = t >> 6;
    const int l = t & 63;
    const int m = l & 15, g = l >> 4;
    f32x4 acc = {0.f, 0.f, 0.f, 0.f};
    const uint4* Bp = (const uint4*)CCf + (size_t)w * 16 * 64 + l;
    #pragma unroll
    for (int s = 0; s < 16; ++s) {
      uint4 bu = Bp[(size_t)s * 64];
      uint4 au = *(const uint4*)&ws16[m][s * 16 + g * 4];
      union { uint4 u; short8v v; } A, B;
      A.u = au; B.u = bu;
      acc = __builtin_amdgcn_mfma_f32_16x16x32_bf16(A.v, B.v, acc, 0, 0, 0);
    }
    // D: col = w*16 + (l&15), row(batch) = g*4 + r  ; fuse bias + leaky relu
    float bias = bo[w * 16 + m];
    #pragma unroll
    for (int r = 0; r < 4; ++r) {
      float val = acc[r] + bias;
      val = val > 0.f ? val : 0.01f * val;
      out[(size_t)(b0 + g * 4 + r) * DD + w * 16 + m] = val;
    }
  }
}

// ---------------------------------------------------------------------------
extern "C" void kernel_launch(void* const* d_in, const int* in_sizes, int n_in,
                              void* d_out, int out_size, void* d_ws, size_t ws_size,
                              hipStream_t stream) {
  const float* x  = (const float*)d_in[0];
  const float* nb = (const float*)d_in[1];
  const float* Wq = (const float*)d_in[2];
  const float* Wk = (const float*)d_in[3];
  const float* Wv = (const float*)d_in[4];
  const float* Wo = (const float*)d_in[5];
  const float* bo = (const float*)d_in[6];
  float* out = (float*)d_out;

  float* ws = (float*)d_ws;
  float* AA = ws;                                        // [128][512] fp32, 256 KB
  unsigned short* CCf = (unsigned short*)(ws + 65536);   // frag-ordered bf16, 128 KB

  precompute_kernel<<<dim3(256, 2), 256, 0, stream>>>(Wq, Wk, Wv, Wo, AA, CCf);
  fused_kernel<<<dim3(NBATCH / BB), NT, 0, stream>>>(x, nb, AA, CCf, bo, out);
}